// Round 2
// baseline (368.121 us; speedup 1.0000x reference)
//
#include <hip/hip_runtime.h>
#include <math.h>

#define NROWS 131072   // B*T = 32*4096
#define KC    512      // codebook size
#define DD    64       // embedding dim
#define NELEM (NROWS * DD)

// d_out layout (floats): [z_q_st: NELEM][indices: NROWS][loss: 1]
#define OUT_IDX_OFF  NELEM
#define OUT_LOSS_OFF (NELEM + NROWS)

// d_ws byte offsets
#define WSO_CNT   0                       // int   flagged-row count
#define WSO_LOSS  8                       // float loss accumulator
#define WSO_WNORM 64                      // float wnorm_np[512] (numpy-exact)
#define WSO_IDX   4096                    // int   idx[NROWS]
#define WSO_LIST  (WSO_IDX + NROWS * 4)   // int   flagList[NROWS]

// ---------------------------------------------------------------------------
// numpy's pairwise sum of squares for 64 contiguous f32 (exact replication of
// FLOAT_pairwise_sum's 8-accumulator scalar tree; ufunc multiply rounds each
// square first). contract(off) is REQUIRED: hipcc defaults -ffp-contract=fast
// which would fuse mul+add into fma and change rounding.
// ---------------------------------------------------------------------------
__device__ __forceinline__ float np_sumsq64(const float* __restrict__ p) {
#pragma clang fp contract(off)
  float r0 = p[0] * p[0];
  float r1 = p[1] * p[1];
  float r2 = p[2] * p[2];
  float r3 = p[3] * p[3];
  float r4 = p[4] * p[4];
  float r5 = p[5] * p[5];
  float r6 = p[6] * p[6];
  float r7 = p[7] * p[7];
  for (int i = 8; i < 64; i += 8) {
    r0 = r0 + p[i + 0] * p[i + 0];
    r1 = r1 + p[i + 1] * p[i + 1];
    r2 = r2 + p[i + 2] * p[i + 2];
    r3 = r3 + p[i + 3] * p[i + 3];
    r4 = r4 + p[i + 4] * p[i + 4];
    r5 = r5 + p[i + 5] * p[i + 5];
    r6 = r6 + p[i + 6] * p[i + 6];
    r7 = r7 + p[i + 7] * p[i + 7];
  }
  return ((r0 + r1) + (r2 + r3)) + ((r4 + r5) + (r6 + r7));
}

// ---------------------------------------------------------------------------
// Kernel 0: wnorm_np[k] = numpy-exact f32 sum(W[k]^2)
// ---------------------------------------------------------------------------
__global__ void k_wnorm(const float* __restrict__ W, float* __restrict__ wnorm) {
  int k = blockIdx.x * blockDim.x + threadIdx.x;
  if (k >= KC) return;
  wnorm[k] = np_sumsq64(W + (k << 6));
}

// ---------------------------------------------------------------------------
// Kernel 1: f32 screening argmin (drops the row-constant ||z||^2 — doesn't
// affect true ordering). Rows whose best-vs-2nd gap is below margin go to the
// numpy-replication refine pass. Margin 3e-5 covers the reference's f32
// quantization at magnitude ~64 (2 roundings x 2 values <= 1.5e-5) plus our
// screening error (<1e-6) with ~2x headroom.
// ---------------------------------------------------------------------------
__global__ __launch_bounds__(256, 2) void k_argmin(
    const float* __restrict__ z, const float* __restrict__ W,
    const float* __restrict__ wnorm, int* __restrict__ idxOut,
    int* __restrict__ flagList, int* __restrict__ flagCnt) {
  int row = blockIdx.x * blockDim.x + threadIdx.x;  // grid sized exactly
  const float* zr = z + ((long)row << 6);

  float zl[DD];
#pragma unroll
  for (int d = 0; d < DD; d += 4) {
    float4 v = *(const float4*)(zr + d);
    zl[d + 0] = v.x; zl[d + 1] = v.y; zl[d + 2] = v.z; zl[d + 3] = v.w;
  }

  float best1 = 1e30f, best2 = 1e30f;
  int bi = 0;

  for (int k = 0; k < KC; k += 4) {
    const float* w0 = W + ((k + 0) << 6);
    const float* w1 = W + ((k + 1) << 6);
    const float* w2 = W + ((k + 2) << 6);
    const float* w3 = W + ((k + 3) << 6);
    float a00 = 0.f, a01 = 0.f, a10 = 0.f, a11 = 0.f;
    float a20 = 0.f, a21 = 0.f, a30 = 0.f, a31 = 0.f;
#pragma unroll
    for (int d = 0; d < DD; d += 2) {
      a00 = fmaf(zl[d], w0[d], a00);  a01 = fmaf(zl[d + 1], w0[d + 1], a01);
      a10 = fmaf(zl[d], w1[d], a10);  a11 = fmaf(zl[d + 1], w1[d + 1], a11);
      a20 = fmaf(zl[d], w2[d], a20);  a21 = fmaf(zl[d + 1], w2[d + 1], a21);
      a30 = fmaf(zl[d], w3[d], a30);  a31 = fmaf(zl[d + 1], w3[d + 1], a31);
    }
    float s0 = fmaf(-2.0f, a00 + a01, wnorm[k + 0]);
    float s1 = fmaf(-2.0f, a10 + a11, wnorm[k + 1]);
    float s2 = fmaf(-2.0f, a20 + a21, wnorm[k + 2]);
    float s3 = fmaf(-2.0f, a30 + a31, wnorm[k + 3]);
    // strictly-less keeps first occurrence; processed in ascending k
    if (s0 < best1) { best2 = best1; best1 = s0; bi = k + 0; } else best2 = fminf(best2, s0);
    if (s1 < best1) { best2 = best1; best1 = s1; bi = k + 1; } else best2 = fminf(best2, s1);
    if (s2 < best1) { best2 = best1; best1 = s2; bi = k + 2; } else best2 = fminf(best2, s2);
    if (s3 < best1) { best2 = best1; best1 = s3; bi = k + 3; } else best2 = fminf(best2, s3);
  }

  idxOut[row] = bi;
  if (best2 - best1 < 3e-5f) {
    int slot = atomicAdd(flagCnt, 1);
    flagList[slot] = row;
  }
}

// ---------------------------------------------------------------------------
// Kernel 2: numpy-f32 replication for flagged rows. One wave per row; lane
// handles k = lane + 64*j. dist_np = fl32( fl32(A + Bnp[k]) - fl32(2*C) ),
// A = numpy-tree sum(z^2) in f32, C = f64 dot rounded once. argmin with
// first-index tie-break (matches np.argmin on quantized ties).
// ---------------------------------------------------------------------------
__global__ void k_refine(const float* __restrict__ z, const float* __restrict__ W,
                         const float* __restrict__ wnp, int* __restrict__ idxOut,
                         const int* __restrict__ flagList,
                         const int* __restrict__ flagCnt) {
  int nflag = *flagCnt;
  int lane = threadIdx.x & 63;
  int wave = (blockIdx.x * blockDim.x + threadIdx.x) >> 6;
  int nWaves = (gridDim.x * blockDim.x) >> 6;

  for (int f = wave; f < nflag; f += nWaves) {
    int row = flagList[f];
    const float* zr = z + ((long)row << 6);
    float A = np_sumsq64(zr);

    float best = 1e30f;
    int bk = 0x7fffffff;
#pragma unroll
    for (int j = 0; j < KC / 64; j++) {
      int k = lane + (j << 6);
      const float* wk = W + (k << 6);
      double cd = 0.0;
      for (int d = 0; d < DD; d++) cd = fma((double)zr[d], (double)wk[d], cd);
      float twoC = (float)(2.0 * cd);  // single rounding of 2*C_true
      float dist;
      {
#pragma clang fp contract(off)
        float t1 = A + wnp[k];
        dist = t1 - twoC;
      }
      if (dist < best || (dist == best && k < bk)) { best = dist; bk = k; }
    }
    // wave argmin with first-index tie-break
    for (int off = 1; off < 64; off <<= 1) {
      float ov = __shfl_xor(best, off, 64);
      int ok = __shfl_xor(bk, off, 64);
      if (ov < best || (ov == best && ok < bk)) { best = ov; bk = ok; }
    }
    if (lane == 0) idxOut[row] = bk;
  }
}

// ---------------------------------------------------------------------------
// Kernel 3: epilogue. z_q_st = z + (W[idx] - z), indices as float, loss sums.
// ---------------------------------------------------------------------------
__global__ __launch_bounds__(256) void k_output(
    const float* __restrict__ z, const float* __restrict__ W,
    const int* __restrict__ idx, float* __restrict__ out,
    float* __restrict__ lossSum) {
  int tid = blockIdx.x * blockDim.x + threadIdx.x;
  const int stride = 2048 * 256;  // grid is exactly 2048 x 256
  float acc = 0.f;

  for (int e = tid; e < NELEM; e += stride) {
    int r = e >> 6;
    int d = e & 63;
    int ki = idx[r];
    float w = W[(ki << 6) | d];
    float zv = z[e];
    float t = w - zv;
    float o = zv + t;  // matches reference's z + (z_q - z)
    out[e] = o;
    float dl = zv - o;
    acc = fmaf(dl, dl, acc);
    if (d == 0) out[OUT_IDX_OFF + r] = (float)ki;
  }

  for (int off = 32; off > 0; off >>= 1) acc += __shfl_down(acc, off, 64);
  __shared__ float red[4];
  if ((threadIdx.x & 63) == 0) red[threadIdx.x >> 6] = acc;
  __syncthreads();
  if (threadIdx.x == 0) {
    float b = (red[0] + red[1]) + (red[2] + red[3]);
    atomicAdd(lossSum, b);
  }
}

// ---------------------------------------------------------------------------
// Kernel 4: finalize loss
// ---------------------------------------------------------------------------
__global__ void k_finalize(const float* __restrict__ lossSum, float* __restrict__ out) {
  out[OUT_LOSS_OFF] = 0.25f * (*lossSum) / (float)NELEM;
}

extern "C" void kernel_launch(void* const* d_in, const int* in_sizes, int n_in,
                              void* d_out, int out_size, void* d_ws, size_t ws_size,
                              hipStream_t stream) {
  const float* z = (const float*)d_in[0];
  const float* W = (const float*)d_in[1];
  float* out = (float*)d_out;
  char* ws = (char*)d_ws;

  int* flagCnt = (int*)(ws + WSO_CNT);
  float* lossSum = (float*)(ws + WSO_LOSS);
  float* wnorm = (float*)(ws + WSO_WNORM);
  int* idx = (int*)(ws + WSO_IDX);
  int* flagList = (int*)(ws + WSO_LIST);

  hipMemsetAsync(d_ws, 0, 64, stream);  // zero flagCnt + lossSum

  k_wnorm<<<2, 256, 0, stream>>>(W, wnorm);
  k_argmin<<<NROWS / 256, 256, 0, stream>>>(z, W, wnorm, idx, flagList, flagCnt);
  k_refine<<<128, 256, 0, stream>>>(z, W, wnorm, idx, flagList, flagCnt);
  k_output<<<2048, 256, 0, stream>>>(z, W, idx, out, lossSum);
  k_finalize<<<1, 1, 0, stream>>>(lossSum, out);
}

// Round 3
// 189.244 us; speedup vs baseline: 1.9452x; 1.9452x over previous
//
#include <hip/hip_runtime.h>
#include <hip/hip_bf16.h>
#include <math.h>

#define NROWS 131072   // B*T = 32*4096
#define KC    512      // codebook size
#define DD    64       // embedding dim
#define NELEM (NROWS * DD)

#define OUT_IDX_OFF  NELEM
#define OUT_LOSS_OFF (NELEM + NROWS)

#define MARGIN 3e-5f

// d_ws byte offsets
#define WSO_CNT   0                        // int   flagged-row count
#define WSO_LOSS  8                        // float loss accumulator
#define WSO_WNORM 64                       // float wnorm_np[512]
#define WSO_BH    4096                     // bf16 frags W-hi: 32 tiles x 2 kh x 64 lanes x 8 = 64 KB
#define WSO_BL    (WSO_BH + 65536)         // bf16 frags W-lo: 64 KB
#define WSO_LIST  (WSO_BL + 65536)         // int flagList[NROWS]

typedef __attribute__((ext_vector_type(8))) short short8;
typedef __attribute__((ext_vector_type(4))) float f32x4;

// ---------------------------------------------------------------------------
// bf16 helpers (RNE via __float2bfloat16)
// ---------------------------------------------------------------------------
__device__ __forceinline__ short f2bf_bits(float f) {
  __hip_bfloat16 h = __float2bfloat16(f);
  short s; __builtin_memcpy(&s, &h, 2); return s;
}
__device__ __forceinline__ float bfbits2f(short s) {
  __hip_bfloat16 h; __builtin_memcpy(&h, &s, 2);
  return __bfloat162float(h);
}
// split 8 consecutive f32 into bf16 hi + bf16 lo(residual)
__device__ __forceinline__ void cvt8(const float* __restrict__ p, short8& hi, short8& lo) {
#pragma unroll
  for (int j = 0; j < 8; j++) {
    float f = p[j];
    short hb = f2bf_bits(f);
    float r = f - bfbits2f(hb);
    hi[j] = hb;
    lo[j] = f2bf_bits(r);
  }
}

// ---------------------------------------------------------------------------
// numpy's pairwise sum of squares for 64 contiguous f32 (8-accumulator tree).
// contract(off) REQUIRED (hipcc default -ffp-contract=fast would fuse).
// ---------------------------------------------------------------------------
__device__ __forceinline__ float np_sumsq64(const float* __restrict__ p) {
#pragma clang fp contract(off)
  float r0 = p[0] * p[0], r1 = p[1] * p[1], r2 = p[2] * p[2], r3 = p[3] * p[3];
  float r4 = p[4] * p[4], r5 = p[5] * p[5], r6 = p[6] * p[6], r7 = p[7] * p[7];
  for (int i = 8; i < 64; i += 8) {
    r0 = r0 + p[i + 0] * p[i + 0];
    r1 = r1 + p[i + 1] * p[i + 1];
    r2 = r2 + p[i + 2] * p[i + 2];
    r3 = r3 + p[i + 3] * p[i + 3];
    r4 = r4 + p[i + 4] * p[i + 4];
    r5 = r5 + p[i + 5] * p[i + 5];
    r6 = r6 + p[i + 6] * p[i + 6];
    r7 = r7 + p[i + 7] * p[i + 7];
  }
  return ((r0 + r1) + (r2 + r3)) + ((r4 + r5) + (r6 + r7));
}

// ---------------------------------------------------------------------------
// Kernel 0: prep. (a) W -> MFMA-B-fragment-major bf16 hi/lo arrays.
// B[k=d][n=cw] fragment for 16x16x32: lane L holds B[(L>>4)*8+j][L&15], j=0..7.
// Element (tile t, khalf h, lane L, j) = W[cw = t*16+(L&15)][d = 32h+(L>>4)*8+j].
// (b) wnorm_np[k] = numpy-exact sum(W[k]^2).
// ---------------------------------------------------------------------------
__global__ void k_prep(const float* __restrict__ W, short8* __restrict__ Bh,
                       short8* __restrict__ Bl, float* __restrict__ wnorm) {
  int gtid = blockIdx.x * blockDim.x + threadIdx.x;  // 0..4095
  int t = gtid >> 7, rem = gtid & 127;
  int h = rem >> 6, L = rem & 63;
  int cw = (t << 4) + (L & 15);
  int dbase = (h << 5) + ((L >> 4) << 3);
  short8 hi, lo;
  cvt8(W + (cw << 6) + dbase, hi, lo);
  Bh[gtid] = hi;  // gtid == ((t*2+h)*64 + L)
  Bl[gtid] = lo;
  if (gtid < KC) wnorm[gtid] = np_sumsq64(W + (gtid << 6));
}

// ---------------------------------------------------------------------------
// Kernel 1: fused MFMA screen + argmin + epilogue.
// Wave handles 64 rows (4 M-tiles of 16). A frags built in-register from z
// (split bf16 hi/lo); B frags streamed from prepped global arrays (L2-hot).
// score_k = wnorm_np[k] - 2*(zh.wh + zl.wh + zh.wl)  [drops row-const ||z||^2;
// error <= ~3e-6 abs, covered by MARGIN]. Per-lane best/second/idx over its
// col slice (ascending k -> strict < keeps first index), xor-butterfly merge
// over the 16 col-lanes with index tie-break. Near-ties flagged for refine.
// Then writes z_q_st, idx-as-float, and loss partial for all 64 rows.
// ---------------------------------------------------------------------------
__global__ __launch_bounds__(256) void k_screen(
    const float* __restrict__ z, const float* __restrict__ W,
    const short8* __restrict__ Bh, const short8* __restrict__ Bl,
    const float* __restrict__ wnorm, float* __restrict__ out,
    int* __restrict__ flagList, int* __restrict__ flagCnt,
    float* __restrict__ lossSum) {
  const int lane = threadIdx.x & 63;
  const int wave = threadIdx.x >> 6;
  const int rowBase = blockIdx.x * 256 + wave * 64;
  const int m = lane & 15, quad = lane >> 4;

  // ---- A fragments: zh/zl for 4 M-tiles x 2 k-halves ----
  short8 Ah[4][2], Al[4][2];
#pragma unroll
  for (int mt = 0; mt < 4; mt++) {
    const float* zp = z + (size_t)(rowBase + (mt << 4) + m) * DD + (quad << 3);
#pragma unroll
    for (int h = 0; h < 2; h++) cvt8(zp + (h << 5), Ah[mt][h], Al[mt][h]);
  }

  float b1[4][4], b2[4][4];
  int bi[4][4];
#pragma unroll
  for (int mt = 0; mt < 4; mt++)
#pragma unroll
    for (int r = 0; r < 4; r++) { b1[mt][r] = 1e30f; b2[mt][r] = 1e30f; bi[mt][r] = 0; }

  // ---- main loop over 32 codeword tiles ----
  for (int t = 0; t < 32; t++) {
    short8 Bhf[2], Blf[2];
#pragma unroll
    for (int h = 0; h < 2; h++) {
      Bhf[h] = Bh[((t * 2 + h) << 6) + lane];
      Blf[h] = Bl[((t * 2 + h) << 6) + lane];
    }
    float wn = wnorm[(t << 4) + m];

    f32x4 acc[4] = {{0.f, 0.f, 0.f, 0.f}, {0.f, 0.f, 0.f, 0.f},
                    {0.f, 0.f, 0.f, 0.f}, {0.f, 0.f, 0.f, 0.f}};
#pragma unroll
    for (int h = 0; h < 2; h++) {
#pragma unroll
      for (int mt = 0; mt < 4; mt++)
        acc[mt] = __builtin_amdgcn_mfma_f32_16x16x32_bf16(Ah[mt][h], Bhf[h], acc[mt], 0, 0, 0);
#pragma unroll
      for (int mt = 0; mt < 4; mt++)
        acc[mt] = __builtin_amdgcn_mfma_f32_16x16x32_bf16(Al[mt][h], Bhf[h], acc[mt], 0, 0, 0);
#pragma unroll
      for (int mt = 0; mt < 4; mt++)
        acc[mt] = __builtin_amdgcn_mfma_f32_16x16x32_bf16(Ah[mt][h], Blf[h], acc[mt], 0, 0, 0);
    }

    int colv = (t << 4) + m;
#pragma unroll
    for (int mt = 0; mt < 4; mt++)
#pragma unroll
      for (int r = 0; r < 4; r++) {
        float s = fmaf(-2.0f, acc[mt][r], wn);
        if (s < b1[mt][r]) { b2[mt][r] = b1[mt][r]; b1[mt][r] = s; bi[mt][r] = colv; }
        else b2[mt][r] = fminf(b2[mt][r], s);
      }
  }

  // ---- merge across the 16 col-lanes (xor butterfly within quad group) ----
#pragma unroll
  for (int off = 1; off < 16; off <<= 1) {
#pragma unroll
    for (int mt = 0; mt < 4; mt++)
#pragma unroll
      for (int r = 0; r < 4; r++) {
        float o1 = __shfl_xor(b1[mt][r], off, 64);
        float o2 = __shfl_xor(b2[mt][r], off, 64);
        int oi = __shfl_xor(bi[mt][r], off, 64);
        if (o1 < b1[mt][r] || (o1 == b1[mt][r] && oi < bi[mt][r])) {
          b2[mt][r] = fminf(b1[mt][r], o2);
          b1[mt][r] = o1; bi[mt][r] = oi;
        } else {
          b2[mt][r] = fminf(b2[mt][r], o1);
        }
      }
  }

  // ---- fused epilogue: z_q_st, idx, loss, flags for this wave's 64 rows ----
  float lossAcc = 0.f;
#pragma unroll
  for (int mt = 0; mt < 4; mt++)
#pragma unroll
    for (int lr = 0; lr < 16; lr++) {
      const int q = lr >> 2, r = lr & 3;
      int ki = __shfl(bi[mt][r], q << 4, 64);
      float b1r = __shfl(b1[mt][r], q << 4, 64);
      float b2r = __shfl(b2[mt][r], q << 4, 64);
      int row = rowBase + (mt << 4) + lr;
      float zv = z[(size_t)row * DD + lane];
      float w = W[(ki << 6) + lane];
      float tt = w - zv;
      float o = zv + tt;  // matches reference z + (z_q - z)
      out[(size_t)row * DD + lane] = o;
      float dl = zv - o;
      lossAcc = fmaf(dl, dl, lossAcc);
      if (lane == 0) {
        out[OUT_IDX_OFF + row] = (float)ki;
        if (b2r - b1r < MARGIN) {
          int slot = atomicAdd(flagCnt, 1);
          flagList[slot] = row;
        }
      }
    }

#pragma unroll
  for (int off = 1; off < 64; off <<= 1) lossAcc += __shfl_xor(lossAcc, off, 64);
  if (lane == 0) atomicAdd(lossSum, lossAcc);
}

// ---------------------------------------------------------------------------
// Kernel 2: numpy-f32 replication for flagged rows + patch out/loss.
// dist_np = fl32( fl32(A + wnp[k]) - fl32(2*C) ), C = f64 dot rounded once.
// ---------------------------------------------------------------------------
__global__ void k_refine(const float* __restrict__ z, const float* __restrict__ W,
                         const float* __restrict__ wnp, float* __restrict__ out,
                         const int* __restrict__ flagList,
                         const int* __restrict__ flagCnt,
                         float* __restrict__ lossSum) {
  int nflag = *flagCnt;
  int lane = threadIdx.x & 63;
  int wave = (blockIdx.x * blockDim.x + threadIdx.x) >> 6;
  int nWaves = (gridDim.x * blockDim.x) >> 6;

  for (int f = wave; f < nflag; f += nWaves) {
    int row = flagList[f];
    const float* zr = z + (size_t)row * DD;
    float A = np_sumsq64(zr);

    float best = 1e30f;
    int bk = 0x7fffffff;
#pragma unroll
    for (int j = 0; j < KC / 64; j++) {
      int k = lane + (j << 6);
      const float* wk = W + (k << 6);
      double cd = 0.0;
      for (int d = 0; d < DD; d++) cd = fma((double)zr[d], (double)wk[d], cd);
      float twoC = (float)(2.0 * cd);
      float dist;
      {
#pragma clang fp contract(off)
        float t1 = A + wnp[k];
        dist = t1 - twoC;
      }
      if (dist < best || (dist == best && k < bk)) { best = dist; bk = k; }
    }
#pragma unroll
    for (int off = 1; off < 64; off <<= 1) {
      float ov = __shfl_xor(best, off, 64);
      int ok = __shfl_xor(bk, off, 64);
      if (ov < best || (ov == best && ok < bk)) { best = ov; bk = ok; }
    }

    int kold = (int)out[OUT_IDX_OFF + row];
    if (bk != kold) {
      float zv = zr[lane];
      float wN = W[(bk << 6) + lane];
      float oOld = out[(size_t)row * DD + lane];
      float tN = wN - zv;
      float oN = zv + tN;
      out[(size_t)row * DD + lane] = oN;
      float dN = zv - oN, dO = zv - oOld;
      float delta = dN * dN - dO * dO;
#pragma unroll
      for (int off = 1; off < 64; off <<= 1) delta += __shfl_xor(delta, off, 64);
      if (lane == 0) {
        atomicAdd(lossSum, delta);
        out[OUT_IDX_OFF + row] = (float)bk;
      }
    }
  }
}

// ---------------------------------------------------------------------------
// Kernel 3: finalize loss
// ---------------------------------------------------------------------------
__global__ void k_finalize(const float* __restrict__ lossSum, float* __restrict__ out) {
  out[OUT_LOSS_OFF] = 0.25f * (*lossSum) / (float)NELEM;
}

extern "C" void kernel_launch(void* const* d_in, const int* in_sizes, int n_in,
                              void* d_out, int out_size, void* d_ws, size_t ws_size,
                              hipStream_t stream) {
  const float* z = (const float*)d_in[0];
  const float* W = (const float*)d_in[1];
  float* out = (float*)d_out;
  char* ws = (char*)d_ws;

  int* flagCnt = (int*)(ws + WSO_CNT);
  float* lossSum = (float*)(ws + WSO_LOSS);
  float* wnorm = (float*)(ws + WSO_WNORM);
  short8* Bh = (short8*)(ws + WSO_BH);
  short8* Bl = (short8*)(ws + WSO_BL);
  int* flagList = (int*)(ws + WSO_LIST);

  hipMemsetAsync(d_ws, 0, 64, stream);  // zero flagCnt + lossSum

  k_prep<<<16, 256, 0, stream>>>(W, Bh, Bl, wnorm);
  k_screen<<<NROWS / 256, 256, 0, stream>>>(z, W, Bh, Bl, wnorm, out,
                                            flagList, flagCnt, lossSum);
  k_refine<<<256, 256, 0, stream>>>(z, W, wnorm, out, flagList, flagCnt, lossSum);
  k_finalize<<<1, 1, 0, stream>>>(lossSum, out);
}